// Round 15
// baseline (194.102 us; speedup 1.0000x reference)
//
#include <hip/hip_runtime.h>
#include <hip/hip_fp8.h>

#define N_NODES 100000
#define N_EDGES 1250000
#define F_IN    128
#define H_DIM   64
#define N_CLS   10
#define N_GRAPH 1000

#define NBKT      ((N_NODES + 255) / 256)   // 391 dst-buckets of 256 nodes
#define BKT_CAP   3584                      // >= max bucket load (3200 + 6.8 sigma)
#define BINS_CAP  (NBKT * BKT_CAP)
#define BIN_T     16
#define BIN_CHUNK (256 * BIN_T)             // 4096 edges per block
#define BIN_NB    ((N_EDGES + BIN_CHUNK - 1) / BIN_CHUNK)

#define PLANE_BYTES ((size_t)N_NODES * 32)  // one half-feature fp8 plane (3.2 MB)
#define PLANE_U4    (N_NODES * 2)           // 16B elems per plane (200000)
#define AGG_NB      ((N_NODES + 63) / 64)   // 1563 blocks (64 nodes each)

typedef __attribute__((ext_vector_type(8))) short bf16x8;
typedef __attribute__((ext_vector_type(4))) float f32x4;
typedef __attribute__((ext_vector_type(2))) float f32x2;
typedef __attribute__((ext_vector_type(2))) unsigned int u32x2;
typedef __attribute__((ext_vector_type(4))) unsigned int u32x4;

__device__ __forceinline__ unsigned short f2bf(float f) {  // RNE fp32 -> bf16
    unsigned int u = __builtin_bit_cast(unsigned int, f);
    u += 0x7FFFu + ((u >> 16) & 1u);
    return (unsigned short)(u >> 16);
}
__device__ __forceinline__ float bf2f(unsigned short h) {
    unsigned int u = (unsigned int)h << 16;
    return __builtin_bit_cast(float, u);
}
__device__ __forceinline__ float bflo(unsigned int g) {
    return __builtin_bit_cast(float, g << 16);
}
__device__ __forceinline__ float bfhi(unsigned int g) {
    return __builtin_bit_cast(float, g & 0xFFFF0000u);
}
__device__ __forceinline__ unsigned char ftofp8(float f) {
    __hip_fp8_e4m3 v(f); return v.__x;
}

// ---------------- setup: btail init + weight packing ----------------

__global__ void setup(const float* __restrict__ W1, const float* __restrict__ W2,
                      unsigned short* __restrict__ Wp1, unsigned short* __restrict__ Wp2,
                      int* __restrict__ btail) {
    int idx = blockIdx.x * 256 + threadIdx.x;   // 0..2047
    if (idx < 1024) {                           // W1: K=128 -> 4 chunks x 4 tiles
        int l = idx & 63, tc = idx >> 6;
        int c = tc & 3, t = tc >> 2;
        for (int j = 0; j < 8; ++j)
            Wp1[idx * 8 + j] = f2bf(W1[(c * 32 + (l >> 4) * 8 + j) * H_DIM + t * 16 + (l & 15)]);
    } else if (idx < 1536) {                    // W2: K=64 -> 2 chunks x 4 tiles
        int i2 = idx - 1024;
        int l = i2 & 63, tc = i2 >> 6;
        int c = tc & 1, t = tc >> 1;
        for (int j = 0; j < 8; ++j)
            Wp2[i2 * 8 + j] = f2bf(W2[(c * 32 + (l >> 4) * 8 + j) * H_DIM + t * 16 + (l & 15)]);
    } else if (idx - 1536 < NBKT) {
        int b = idx - 1536;
        btail[b] = b * BKT_CAP;
    }
}

// ---------------- CSR build (fixed-capacity buckets) ----------------

__global__ void bin_edges(const int* __restrict__ ei, int* __restrict__ btail,
                          unsigned int* __restrict__ bins) {
    __shared__ int hist[NBKT];
    __shared__ int base[NBKT];
    int tid = threadIdx.x;
    for (int b = tid; b < NBKT; b += 256) hist[b] = 0;
    __syncthreads();
    int e0 = blockIdx.x * BIN_CHUNK;
    unsigned short rank[BIN_T];
#pragma unroll
    for (int t = 0; t < BIN_T; ++t) {
        int e = e0 + t * 256 + tid;
        int r = 0;
        if (e < N_EDGES) {
            int b = ei[N_EDGES + e] >> 8;
            r = atomicAdd(&hist[b], 1);
        }
        rank[t] = (unsigned short)r;
    }
    __syncthreads();
    for (int b = tid; b < NBKT; b += 256) {
        int c = hist[b];
        base[b] = c ? atomicAdd(&btail[b], c) : 0;
    }
    __syncthreads();
#pragma unroll
    for (int t = 0; t < BIN_T; ++t) {
        int e = e0 + t * 256 + tid;
        if (e < N_EDGES) {
            int src = ei[e];
            int dst = ei[N_EDGES + e];
            int b = dst >> 8;
            int idx = base[b] + (int)rank[t];
            if (idx >= BINS_CAP) idx = BINS_CAP - 1;   // impossible-overflow guard
            bins[idx] = (unsigned int)src | ((unsigned int)(dst & 255) << 17);
        }
    }
}

__global__ void bucket_build(const unsigned int* __restrict__ bins, const int* __restrict__ btail,
                             int* __restrict__ rowdeg, float* __restrict__ dinv,
                             int* __restrict__ colsrc) {
    __shared__ int cnt[256];
    __shared__ int pfx[256];
    __shared__ int cur[256];
    __shared__ int ws[4];
    int bkt  = blockIdx.x;
    int base = bkt << 8;
    int tid  = threadIdx.x;
    int nn   = N_NODES - base; if (nn > 256) nn = 256;
    int pbeg = bkt * BKT_CAP, pend = btail[bkt];

    cnt[tid] = 0; cur[tid] = 0;
    __syncthreads();
    for (int p = pbeg + tid; p < pend; p += 256)
        atomicAdd(&cnt[bins[p] >> 17], 1);
    __syncthreads();

    int lane = tid & 63, wid = tid >> 6;
    int v   = cnt[tid];
    int inc = v;
    for (int off = 1; off < 64; off <<= 1) {
        int u = __shfl_up(inc, off);
        if (lane >= off) inc += u;
    }
    if (lane == 63) ws[wid] = inc;
    __syncthreads();
    int woff = 0;
    for (int w = 0; w < wid; ++w) woff += ws[w];
    pfx[tid] = woff + inc - v;   // exclusive prefix within bucket
    __syncthreads();

    if (tid < nn) {
        rowdeg[base + tid] = (pbeg + pfx[tid]) | (v << 22);
        dinv[base + tid]   = rsqrtf((float)v + 1.0f);   // +1 self-loop
    }

    for (int p = pbeg + tid; p < pend; p += 256) {
        unsigned int pk = bins[p];
        int ld  = (int)(pk >> 17);
        int loc = atomicAdd(&cur[ld], 1);
        colsrc[pbeg + pfx[ld] + loc] = (int)(pk & 0x1FFFFu);
    }
}

// ---------------- MFMA GEMM -> two fp8 half-feature planes ----------------
// Y plane p holds features [p*32, p*32+32) : Y[p*PLANE + row*32 + (f - p*32)].

template<int K, bool ABF>
__global__ void gemm_mfma(const void* __restrict__ Ap, const unsigned short* __restrict__ Wp,
                          const float* __restrict__ dinv, unsigned char* __restrict__ Y) {
    int lane = threadIdx.x & 63;
    int wave = threadIdx.x >> 6;
    int l16 = lane & 15, lhi = lane >> 4;
    int row0 = blockIdx.x * 64 + wave * 16;
    int arow = row0 + l16;
    bool aok = (arow < N_NODES);

    f32x4 acc[4];
#pragma unroll
    for (int t = 0; t < 4; ++t) acc[t] = (f32x4){0.f, 0.f, 0.f, 0.f};

#pragma unroll
    for (int c = 0; c < K / 32; ++c) {
        bf16x8 a;
        if (ABF) {
            if (aok) a = __builtin_nontemporal_load(
                (const bf16x8*)((const unsigned short*)Ap + (size_t)arow * K + c * 32 + lhi * 8));
            else     a = (bf16x8){0, 0, 0, 0, 0, 0, 0, 0};
        } else {
            if (aok) {
                const float* Af = (const float*)Ap + (size_t)arow * K + c * 32 + lhi * 8;
                f32x4 f0 = __builtin_nontemporal_load((const f32x4*)(Af));
                f32x4 f1 = __builtin_nontemporal_load((const f32x4*)(Af + 4));
                a = (bf16x8){(short)f2bf(f0.x), (short)f2bf(f0.y), (short)f2bf(f0.z), (short)f2bf(f0.w),
                             (short)f2bf(f1.x), (short)f2bf(f1.y), (short)f2bf(f1.z), (short)f2bf(f1.w)};
            } else a = (bf16x8){0, 0, 0, 0, 0, 0, 0, 0};
        }
#pragma unroll
        for (int t = 0; t < 4; ++t) {
            bf16x8 b = *(const bf16x8*)(Wp + ((size_t)(t * (K / 32) + c) * 64 + lane) * 8);
            acc[t] = __builtin_amdgcn_mfma_f32_16x16x32_bf16(a, b, acc[t], 0, 0, 0);
        }
    }

#pragma unroll
    for (int r = 0; r < 4; ++r) {
        int row = row0 + lhi * 4 + r;
        if (row < N_NODES) {
            float dv = dinv[row];
#pragma unroll
            for (int t = 0; t < 4; ++t)
                Y[(size_t)(t >> 1) * PLANE_BYTES + (size_t)row * 32 + (t & 1) * 16 + l16] =
                    ftofp8(acc[t][r] * dv);
        }
    }
}

// ---------------- aggregation over one half-feature plane ----------------
// 16 nodes/wave, 4 lanes/node; lane f8 owns features f8*8..f8*8+7 of this plane.
// Prologue streams the 3.2MB plane linearly into L2 (stripe per blockIdx>>3,
// assuming round-robin XCD dispatch); stream-once data uses non-temporal ops.

template<int RELU>
__global__ void __launch_bounds__(256, 8)
agg_plane(const unsigned char* __restrict__ Hp,    // plane base [N][32] fp8
          const float* __restrict__ dinv,
          const int* __restrict__ rowdeg, const int* __restrict__ colsrc,
          const float* __restrict__ biasp,         // bias + p*32
          unsigned short* __restrict__ Zp) {       // z + p*32 (row stride 64 shorts)
    // --- linear L2 warm of this plane ---
    {
        const u32x4* pl = (const u32x4*)Hp;
        int base = (blockIdx.x >> 3) * 1024 + threadIdx.x;
#pragma unroll
        for (int i = 0; i < 4; ++i) {
            int idx = base + i * 256;
            if (idx < PLANE_U4) {
                u32x4 w = pl[idx];
                asm volatile("" :: "v"(w.x), "v"(w.y), "v"(w.z), "v"(w.w));
            }
        }
    }

    int tid  = threadIdx.x;
    int lane = tid & 63;
    int g    = lane >> 2;               // node group 0..15
    int f8   = lane & 3;                // feature octet within plane
    int node = blockIdx.x * 64 + (tid >> 6) * 16 + g;
    bool ok  = node < N_NODES;

    const u32x2* H = (const u32x2*)Hp;  // 8B granules; 4 per plane-row

    f32x2 a01 = {0.f, 0.f}, a23 = {0.f, 0.f}, a45 = {0.f, 0.f}, a67 = {0.f, 0.f};
    auto acc8 = [&](u32x2 gg) {
        a01 += __builtin_amdgcn_cvt_pk_f32_fp8((int)gg.x, false);
        a23 += __builtin_amdgcn_cvt_pk_f32_fp8((int)gg.x, true);
        a45 += __builtin_amdgcn_cvt_pk_f32_fp8((int)gg.y, false);
        a67 += __builtin_amdgcn_cvt_pk_f32_fp8((int)gg.y, true);
    };

    int p = 0, end = 0;
    if (ok) {
        acc8(H[(size_t)node * 4 + f8]);                      // self term
        int rd = __builtin_nontemporal_load(rowdeg + node);
        p   = rd & 0x3FFFFF;
        end = p + (int)((unsigned)rd >> 22);
    }

    while (__any(p < end)) {
        bool v0 = p < end;
        bool v1 = p + 1 < end;
        int s0 = v0 ? __builtin_nontemporal_load(colsrc + p)     : 0;
        int s1 = v1 ? __builtin_nontemporal_load(colsrc + p + 1) : 0;
        if (v0) acc8(H[(size_t)s0 * 4 + f8]);
        if (v1) acc8(H[(size_t)s1 * 4 + f8]);
        p += 2;
    }

    if (ok) {
        float dv = dinv[node];
        float4 b0 = *(const float4*)(biasp + f8 * 8);
        float4 b1 = *(const float4*)(biasp + f8 * 8 + 4);
        float v0 = a01.x * dv + b0.x, v1 = a01.y * dv + b0.y;
        float v2 = a23.x * dv + b0.z, v3 = a23.y * dv + b0.w;
        float v4 = a45.x * dv + b1.x, v5 = a45.y * dv + b1.y;
        float v6 = a67.x * dv + b1.z, v7 = a67.y * dv + b1.w;
        if (RELU) {
            v0 = fmaxf(v0, 0.f); v1 = fmaxf(v1, 0.f); v2 = fmaxf(v2, 0.f); v3 = fmaxf(v3, 0.f);
            v4 = fmaxf(v4, 0.f); v5 = fmaxf(v5, 0.f); v6 = fmaxf(v6, 0.f); v7 = fmaxf(v7, 0.f);
        }
        u32x4 pk;
        pk.x = (unsigned int)f2bf(v0) | ((unsigned int)f2bf(v1) << 16);
        pk.y = (unsigned int)f2bf(v2) | ((unsigned int)f2bf(v3) << 16);
        pk.z = (unsigned int)f2bf(v4) | ((unsigned int)f2bf(v5) << 16);
        pk.w = (unsigned int)f2bf(v6) | ((unsigned int)f2bf(v7) << 16);
        // byte addr = node*128 + f8*16  (Zp pre-offset by plane*32 shorts)
        __builtin_nontemporal_store(pk, ((u32x4*)Zp) + (size_t)node * 8 + f8);
    }
}

// ---------------- fused pooling + head (batch sorted -> contiguous segments) ----------------

__global__ void pool_head(const unsigned short* __restrict__ Hb, const int* __restrict__ batch,
                          const float* __restrict__ Wl, const float* __restrict__ bl,
                          float* __restrict__ out) {
    int g   = blockIdx.x;
    int tid = threadIdx.x;   // 0..255

    auto lb = [&](int key) {
        int lo = 0, hi = N_NODES;
        while (lo < hi) {
            int mid = (lo + hi) >> 1;
            if (batch[mid] < key) lo = mid + 1; else hi = mid;
        }
        return lo;
    };
    int beg = lb(g);
    int end = lb(g + 1);

    int fq = tid & 15;       // feature quad (features 4fq..4fq+3)
    int rg = tid >> 4;       // 16 row groups
    const u32x2* H = (const u32x2*)Hb;
    float4 acc = {0.f, 0.f, 0.f, 0.f};
    for (int i = beg + rg; i < end; i += 16) {
        u32x2 gg = __builtin_nontemporal_load(H + (size_t)i * 16 + fq);
        acc.x += bflo(gg.x); acc.y += bfhi(gg.x);
        acc.z += bflo(gg.y); acc.w += bfhi(gg.y);
    }

    __shared__ float4 s[16][16];
    __shared__ float  pl[64];
    s[rg][fq] = acc;
    __syncthreads();

    if (tid < 16) {
        float4 t = s[0][tid];
        for (int r = 1; r < 16; ++r) {
            t.x += s[r][tid].x; t.y += s[r][tid].y;
            t.z += s[r][tid].z; t.w += s[r][tid].w;
        }
        float inv = 1.0f / fmaxf((float)(end - beg), 1.0f);
        pl[4 * tid]     = t.x * inv;
        pl[4 * tid + 1] = t.y * inv;
        pl[4 * tid + 2] = t.z * inv;
        pl[4 * tid + 3] = t.w * inv;
    }
    __syncthreads();

    if (tid < 64) {
        float p = pl[tid];
        __shared__ float logits[N_CLS];
        for (int c = 0; c < N_CLS; ++c) {
            float v = p * Wl[tid * N_CLS + c];
            for (int off = 32; off; off >>= 1) v += __shfl_xor(v, off);
            if (tid == 0) logits[c] = v + bl[c];
        }
        if (tid == 0) {
            float m = logits[0];
            for (int c = 1; c < N_CLS; ++c) m = fmaxf(m, logits[c]);
            float sum = 0.f;
            for (int c = 0; c < N_CLS; ++c) sum += expf(logits[c] - m);
            float ls = logf(sum);
            for (int c = 0; c < N_CLS; ++c) out[g * N_CLS + c] = logits[c] - m - ls;
        }
    }
}

// ---------------- launch ----------------

extern "C" void kernel_launch(void* const* d_in, const int* in_sizes, int n_in,
                              void* d_out, int out_size, void* d_ws, size_t ws_size,
                              hipStream_t stream) {
    const float* x     = (const float*)d_in[0];
    const int*   ei    = (const int*)d_in[1];
    const int*   batch = (const int*)d_in[2];
    const float* W1    = (const float*)d_in[3];
    const float* b1    = (const float*)d_in[4];
    const float* W2    = (const float*)d_in[5];
    const float* b2    = (const float*)d_in[6];
    const float* Wl    = (const float*)d_in[7];
    const float* bl    = (const float*)d_in[8];
    float*       out   = (float*)d_out;

    char* p = (char*)d_ws;
    auto alloc = [&](size_t bytes) {
        char* r = p;
        p += (bytes + 255) & ~(size_t)255;
        return r;
    };
    int*            btail  = (int*)            alloc((size_t)NBKT * 4);
    int*            rowdeg = (int*)            alloc((size_t)N_NODES * 4);
    float*          dinv   = (float*)          alloc((size_t)N_NODES * 4);
    int*            colsrc = (int*)            alloc((size_t)BINS_CAP * 4);
    unsigned int*   bins   = (unsigned int*)   alloc((size_t)BINS_CAP * 4);
    unsigned char*  hA8    = (unsigned char*)  alloc(PLANE_BYTES * 2);
    unsigned short* hB     = (unsigned short*) alloc((size_t)N_NODES * H_DIM * 2);
    unsigned short* Wp1    = (unsigned short*) alloc((size_t)1024 * 8 * 2);
    unsigned short* Wp2    = (unsigned short*) alloc((size_t)512 * 8 * 2);

    int gb = (N_NODES + 63) / 64;

    setup       <<<8, 256, 0, stream>>>(W1, W2, Wp1, Wp2, btail);
    bin_edges   <<<BIN_NB, 256, 0, stream>>>(ei, btail, bins);
    bucket_build<<<NBKT, 256, 0, stream>>>(bins, btail, rowdeg, dinv, colsrc);

    gemm_mfma<F_IN, false><<<gb, 256, 0, stream>>>(x, Wp1, dinv, hA8);   // h1' planes
    agg_plane<1><<<AGG_NB, 256, 0, stream>>>(hA8,               dinv, rowdeg, colsrc, b1,      hB);
    agg_plane<1><<<AGG_NB, 256, 0, stream>>>(hA8 + PLANE_BYTES, dinv, rowdeg, colsrc, b1 + 32, hB + 32);
    gemm_mfma<H_DIM, true><<<gb, 256, 0, stream>>>(hB, Wp2, dinv, hA8);  // h2' planes
    agg_plane<0><<<AGG_NB, 256, 0, stream>>>(hA8,               dinv, rowdeg, colsrc, b2,      hB);
    agg_plane<0><<<AGG_NB, 256, 0, stream>>>(hA8 + PLANE_BYTES, dinv, rowdeg, colsrc, b2 + 32, hB + 32);
    pool_head<<<N_GRAPH, 256, 0, stream>>>(hB, batch, Wl, bl, out);
}

// Round 16
// 148.500 us; speedup vs baseline: 1.3071x; 1.3071x over previous
//
#include <hip/hip_runtime.h>
#include <hip/hip_fp8.h>

#define N_NODES 100000
#define N_EDGES 1250000
#define F_IN    128
#define H_DIM   64
#define N_CLS   10
#define N_GRAPH 1000

#define NBKT      ((N_NODES + 255) / 256)   // 391 dst-buckets of 256 nodes
#define BKT_CAP   3584                      // >= max bucket load (3200 + 6.8 sigma)
#define BINS_CAP  (NBKT * BKT_CAP)
#define BIN_T     16
#define BIN_CHUNK (256 * BIN_T)             // 4096 edges per block
#define BIN_NB    ((N_EDGES + BIN_CHUNK - 1) / BIN_CHUNK)

typedef __attribute__((ext_vector_type(8))) short bf16x8;
typedef __attribute__((ext_vector_type(4))) float f32x4;
typedef __attribute__((ext_vector_type(2))) float f32x2;

__device__ __forceinline__ unsigned short f2bf(float f) {  // RNE fp32 -> bf16
    unsigned int u = __builtin_bit_cast(unsigned int, f);
    u += 0x7FFFu + ((u >> 16) & 1u);
    return (unsigned short)(u >> 16);
}
__device__ __forceinline__ float bf2f(unsigned short h) {
    unsigned int u = (unsigned int)h << 16;
    return __builtin_bit_cast(float, u);
}
__device__ __forceinline__ float bflo(unsigned int g) {
    return __builtin_bit_cast(float, g << 16);
}
__device__ __forceinline__ float bfhi(unsigned int g) {
    return __builtin_bit_cast(float, g & 0xFFFF0000u);
}
__device__ __forceinline__ unsigned char ftofp8(float f) {
    __hip_fp8_e4m3 v(f); return v.__x;
}

// ---------------- setup: btail init + weight packing (one kernel) ----------------
// Wp layout: B-frag for (col-tile t, k-chunk c): lane l, elem j holds
// W[c*32 + (l>>4)*8 + j][t*16 + (l&15)], packed at Wp[((t*(K/32)+c)*64+l)*8+j].

__global__ void setup(const float* __restrict__ W1, const float* __restrict__ W2,
                      unsigned short* __restrict__ Wp1, unsigned short* __restrict__ Wp2,
                      int* __restrict__ btail) {
    int idx = blockIdx.x * 256 + threadIdx.x;   // 0..2047
    if (idx < 1024) {                           // W1: K=128 -> 4 chunks x 4 tiles
        int l = idx & 63, tc = idx >> 6;
        int c = tc & 3, t = tc >> 2;
        for (int j = 0; j < 8; ++j)
            Wp1[idx * 8 + j] = f2bf(W1[(c * 32 + (l >> 4) * 8 + j) * H_DIM + t * 16 + (l & 15)]);
    } else if (idx < 1536) {                    // W2: K=64 -> 2 chunks x 4 tiles
        int i2 = idx - 1024;
        int l = i2 & 63, tc = i2 >> 6;
        int c = tc & 1, t = tc >> 1;
        for (int j = 0; j < 8; ++j)
            Wp2[i2 * 8 + j] = f2bf(W2[(c * 32 + (l >> 4) * 8 + j) * H_DIM + t * 16 + (l & 15)]);
    } else if (idx - 1536 < NBKT) {
        int b = idx - 1536;
        btail[b] = b * BKT_CAP;
    }
}

// ---------------- CSR build (fixed-capacity buckets) ----------------

__global__ void bin_edges(const int* __restrict__ ei, int* __restrict__ btail,
                          unsigned int* __restrict__ bins) {
    __shared__ int hist[NBKT];
    __shared__ int base[NBKT];
    int tid = threadIdx.x;
    for (int b = tid; b < NBKT; b += 256) hist[b] = 0;
    __syncthreads();
    int e0 = blockIdx.x * BIN_CHUNK;
    unsigned short rank[BIN_T];
#pragma unroll
    for (int t = 0; t < BIN_T; ++t) {
        int e = e0 + t * 256 + tid;
        int r = 0;
        if (e < N_EDGES) {
            int b = ei[N_EDGES + e] >> 8;
            r = atomicAdd(&hist[b], 1);
        }
        rank[t] = (unsigned short)r;
    }
    __syncthreads();
    for (int b = tid; b < NBKT; b += 256) {
        int c = hist[b];
        base[b] = c ? atomicAdd(&btail[b], c) : 0;
    }
    __syncthreads();
#pragma unroll
    for (int t = 0; t < BIN_T; ++t) {
        int e = e0 + t * 256 + tid;
        if (e < N_EDGES) {
            int src = ei[e];
            int dst = ei[N_EDGES + e];
            int b = dst >> 8;
            int idx = base[b] + (int)rank[t];
            if (idx >= BINS_CAP) idx = BINS_CAP - 1;   // impossible-overflow guard
            bins[idx] = (unsigned int)src | ((unsigned int)(dst & 255) << 17);
        }
    }
}

// One block per bucket: per-node counts (LDS), block scan -> packed rowdeg
// (beg | deg<<22) + dinv, then dense in-bucket scatter into colsrc.
__global__ void bucket_build(const unsigned int* __restrict__ bins, const int* __restrict__ btail,
                             int* __restrict__ rowdeg, float* __restrict__ dinv,
                             int* __restrict__ colsrc) {
    __shared__ int cnt[256];
    __shared__ int pfx[256];
    __shared__ int cur[256];
    __shared__ int ws[4];
    int bkt  = blockIdx.x;
    int base = bkt << 8;
    int tid  = threadIdx.x;
    int nn   = N_NODES - base; if (nn > 256) nn = 256;
    int pbeg = bkt * BKT_CAP, pend = btail[bkt];

    cnt[tid] = 0; cur[tid] = 0;
    __syncthreads();
    for (int p = pbeg + tid; p < pend; p += 256)
        atomicAdd(&cnt[bins[p] >> 17], 1);
    __syncthreads();

    int lane = tid & 63, wid = tid >> 6;
    int v   = cnt[tid];
    int inc = v;
    for (int off = 1; off < 64; off <<= 1) {
        int u = __shfl_up(inc, off);
        if (lane >= off) inc += u;
    }
    if (lane == 63) ws[wid] = inc;
    __syncthreads();
    int woff = 0;
    for (int w = 0; w < wid; ++w) woff += ws[w];
    pfx[tid] = woff + inc - v;   // exclusive prefix within bucket
    __syncthreads();

    if (tid < nn) {
        rowdeg[base + tid] = (pbeg + pfx[tid]) | (v << 22);
        dinv[base + tid]   = rsqrtf((float)v + 1.0f);   // +1 self-loop
    }

    for (int p = pbeg + tid; p < pend; p += 256) {
        unsigned int pk = bins[p];
        int ld  = (int)(pk >> 17);
        int loc = atomicAdd(&cur[ld], 1);
        colsrc[pbeg + pfx[ld] + loc] = (int)(pk & 0x1FFFFu);
    }
}

// ---------------- MFMA GEMM:  Y[row][col] = (A[row][:] @ W[:,col]) * dinv[row] -> fp8 ------

template<int K, bool ABF>
__global__ void gemm_mfma(const void* __restrict__ Ap, const unsigned short* __restrict__ Wp,
                          const float* __restrict__ dinv, unsigned char* __restrict__ Y) {
    int lane = threadIdx.x & 63;
    int wave = threadIdx.x >> 6;
    int l16 = lane & 15, lhi = lane >> 4;
    int row0 = blockIdx.x * 64 + wave * 16;
    int arow = row0 + l16;
    bool aok = (arow < N_NODES);

    f32x4 acc[4];
#pragma unroll
    for (int t = 0; t < 4; ++t) acc[t] = (f32x4){0.f, 0.f, 0.f, 0.f};

#pragma unroll
    for (int c = 0; c < K / 32; ++c) {
        bf16x8 a;
        if (ABF) {
            if (aok) a = *(const bf16x8*)((const unsigned short*)Ap + (size_t)arow * K + c * 32 + lhi * 8);
            else     a = (bf16x8){0, 0, 0, 0, 0, 0, 0, 0};
        } else {
            if (aok) {
                const float* Af = (const float*)Ap + (size_t)arow * K + c * 32 + lhi * 8;
                float4 f0 = *(const float4*)(Af);
                float4 f1 = *(const float4*)(Af + 4);
                a = (bf16x8){(short)f2bf(f0.x), (short)f2bf(f0.y), (short)f2bf(f0.z), (short)f2bf(f0.w),
                             (short)f2bf(f1.x), (short)f2bf(f1.y), (short)f2bf(f1.z), (short)f2bf(f1.w)};
            } else a = (bf16x8){0, 0, 0, 0, 0, 0, 0, 0};
        }
#pragma unroll
        for (int t = 0; t < 4; ++t) {
            bf16x8 b = *(const bf16x8*)(Wp + ((size_t)(t * (K / 32) + c) * 64 + lane) * 8);
            acc[t] = __builtin_amdgcn_mfma_f32_16x16x32_bf16(a, b, acc[t], 0, 0, 0);
        }
    }

#pragma unroll
    for (int r = 0; r < 4; ++r) {
        int row = row0 + lhi * 4 + r;
        if (row < N_NODES) {
            float dv = dinv[row];
#pragma unroll
            for (int t = 0; t < 4; ++t)
                Y[(size_t)row * H_DIM + t * 16 + l16] = ftofp8(acc[t][r] * dv);
        }
    }
}

// ---------------- aggregation: 8 nodes/wave, 8 lanes/node, no LDS, no reduce --------------
// Lane group g (8 lanes) owns node base+g; lane f8 accumulates feature octet 8f8..8f8+7
// across ALL of its node's edges. Exec-masked loads: memory issued == E gathers exactly.
// out = [relu](dinv[i]*(sum_{e:dst=i} h'[src] + h'[i]) + b), h' fp8 pre-scaled; out bf16.

template<int RELU>
__global__ void __launch_bounds__(256, 8)
agg_fp8(const unsigned char* __restrict__ Hq, const float* __restrict__ dinv,
        const int* __restrict__ rowdeg, const int* __restrict__ colsrc,
        const float* __restrict__ bias, unsigned short* __restrict__ Z) {
    int tid  = threadIdx.x;
    int lane = tid & 63;
    int g    = lane >> 3;                 // node group 0..7
    int f8   = lane & 7;                  // feature octet
    int node = blockIdx.x * 32 + (tid >> 6) * 8 + g;   // 3125 blocks x 32 nodes (exact)

    const uint2* H = (const uint2*)Hq;

    f32x2 a01 = {0.f, 0.f}, a23 = {0.f, 0.f}, a45 = {0.f, 0.f}, a67 = {0.f, 0.f};
    auto acc8 = [&](uint2 gg) {
        a01 += __builtin_amdgcn_cvt_pk_f32_fp8((int)gg.x, false);
        a23 += __builtin_amdgcn_cvt_pk_f32_fp8((int)gg.x, true);
        a45 += __builtin_amdgcn_cvt_pk_f32_fp8((int)gg.y, false);
        a67 += __builtin_amdgcn_cvt_pk_f32_fp8((int)gg.y, true);
    };

    acc8(H[(size_t)node * 8 + f8]);       // self term (coalesced across groups)

    int rd  = rowdeg[node];
    int p   = rd & 0x3FFFFF;
    int end = p + (int)((unsigned)rd >> 22);

    while (__any(p < end)) {
        bool v0 = p < end;
        bool v1 = p + 1 < end;
        int s0 = v0 ? colsrc[p]     : 0;  // exec-masked loads
        int s1 = v1 ? colsrc[p + 1] : 0;
        if (v0) {
            uint2 g0 = H[(size_t)s0 * 8 + f8];
            acc8(g0);
        }
        if (v1) {
            uint2 g1 = H[(size_t)s1 * 8 + f8];
            acc8(g1);
        }
        p += 2;
    }

    float dv = dinv[node];
    float4 b0 = *(const float4*)(bias + 8 * f8);
    float4 b1 = *(const float4*)(bias + 8 * f8 + 4);
    float v0 = a01.x * dv + b0.x, v1 = a01.y * dv + b0.y;
    float v2 = a23.x * dv + b0.z, v3 = a23.y * dv + b0.w;
    float v4 = a45.x * dv + b1.x, v5 = a45.y * dv + b1.y;
    float v6 = a67.x * dv + b1.z, v7 = a67.y * dv + b1.w;
    if (RELU) {
        v0 = fmaxf(v0, 0.f); v1 = fmaxf(v1, 0.f); v2 = fmaxf(v2, 0.f); v3 = fmaxf(v3, 0.f);
        v4 = fmaxf(v4, 0.f); v5 = fmaxf(v5, 0.f); v6 = fmaxf(v6, 0.f); v7 = fmaxf(v7, 0.f);
    }
    uint4 pk;
    pk.x = (unsigned int)f2bf(v0) | ((unsigned int)f2bf(v1) << 16);
    pk.y = (unsigned int)f2bf(v2) | ((unsigned int)f2bf(v3) << 16);
    pk.z = (unsigned int)f2bf(v4) | ((unsigned int)f2bf(v5) << 16);
    pk.w = (unsigned int)f2bf(v6) | ((unsigned int)f2bf(v7) << 16);
    *(((uint4*)Z) + (size_t)node * 8 + f8) = pk;
}

// ---------------- fused pooling + head (batch sorted -> contiguous segments) ----------------

__global__ void pool_head(const unsigned short* __restrict__ Hb, const int* __restrict__ batch,
                          const float* __restrict__ Wl, const float* __restrict__ bl,
                          float* __restrict__ out) {
    int g   = blockIdx.x;
    int tid = threadIdx.x;   // 0..255

    auto lb = [&](int key) {
        int lo = 0, hi = N_NODES;
        while (lo < hi) {
            int mid = (lo + hi) >> 1;
            if (batch[mid] < key) lo = mid + 1; else hi = mid;
        }
        return lo;
    };
    int beg = lb(g);
    int end = lb(g + 1);

    int fq = tid & 15;       // feature quad (features 4fq..4fq+3)
    int rg = tid >> 4;       // 16 row groups
    const uint2* H = (const uint2*)Hb;
    float4 acc = {0.f, 0.f, 0.f, 0.f};
    for (int i = beg + rg; i < end; i += 16) {
        uint2 gg = H[(size_t)i * 16 + fq];
        acc.x += bflo(gg.x); acc.y += bfhi(gg.x);
        acc.z += bflo(gg.y); acc.w += bfhi(gg.y);
    }

    __shared__ float4 s[16][16];
    __shared__ float  pl[64];
    s[rg][fq] = acc;
    __syncthreads();

    if (tid < 16) {
        float4 t = s[0][tid];
        for (int r = 1; r < 16; ++r) {
            t.x += s[r][tid].x; t.y += s[r][tid].y;
            t.z += s[r][tid].z; t.w += s[r][tid].w;
        }
        float inv = 1.0f / fmaxf((float)(end - beg), 1.0f);
        pl[4 * tid]     = t.x * inv;
        pl[4 * tid + 1] = t.y * inv;
        pl[4 * tid + 2] = t.z * inv;
        pl[4 * tid + 3] = t.w * inv;
    }
    __syncthreads();

    if (tid < 64) {
        float p = pl[tid];
        __shared__ float logits[N_CLS];
        for (int c = 0; c < N_CLS; ++c) {
            float v = p * Wl[tid * N_CLS + c];
            for (int off = 32; off; off >>= 1) v += __shfl_xor(v, off);
            if (tid == 0) logits[c] = v + bl[c];
        }
        if (tid == 0) {
            float m = logits[0];
            for (int c = 1; c < N_CLS; ++c) m = fmaxf(m, logits[c]);
            float sum = 0.f;
            for (int c = 0; c < N_CLS; ++c) sum += expf(logits[c] - m);
            float ls = logf(sum);
            for (int c = 0; c < N_CLS; ++c) out[g * N_CLS + c] = logits[c] - m - ls;
        }
    }
}

// ---------------- launch ----------------

extern "C" void kernel_launch(void* const* d_in, const int* in_sizes, int n_in,
                              void* d_out, int out_size, void* d_ws, size_t ws_size,
                              hipStream_t stream) {
    const float* x     = (const float*)d_in[0];
    const int*   ei    = (const int*)d_in[1];
    const int*   batch = (const int*)d_in[2];
    const float* W1    = (const float*)d_in[3];
    const float* b1    = (const float*)d_in[4];
    const float* W2    = (const float*)d_in[5];
    const float* b2    = (const float*)d_in[6];
    const float* Wl    = (const float*)d_in[7];
    const float* bl    = (const float*)d_in[8];
    float*       out   = (float*)d_out;

    char* p = (char*)d_ws;
    auto alloc = [&](size_t bytes) {
        char* r = p;
        p += (bytes + 255) & ~(size_t)255;
        return r;
    };
    int*            btail  = (int*)            alloc((size_t)NBKT * 4);
    int*            rowdeg = (int*)            alloc((size_t)N_NODES * 4);
    float*          dinv   = (float*)          alloc((size_t)N_NODES * 4);
    int*            colsrc = (int*)            alloc((size_t)BINS_CAP * 4);
    unsigned int*   bins   = (unsigned int*)   alloc((size_t)BINS_CAP * 4);
    unsigned char*  hA8    = (unsigned char*)  alloc((size_t)N_NODES * H_DIM);
    unsigned short* hB     = (unsigned short*) alloc((size_t)N_NODES * H_DIM * 2);
    unsigned short* Wp1    = (unsigned short*) alloc((size_t)1024 * 8 * 2);
    unsigned short* Wp2    = (unsigned short*) alloc((size_t)512 * 8 * 2);

    int agg_nb = N_NODES / 32;     // 3125 (exact)
    int gb     = (N_NODES + 63) / 64;

    setup       <<<8, 256, 0, stream>>>(W1, W2, Wp1, Wp2, btail);
    bin_edges   <<<BIN_NB, 256, 0, stream>>>(ei, btail, bins);
    bucket_build<<<NBKT, 256, 0, stream>>>(bins, btail, rowdeg, dinv, colsrc);

    gemm_mfma<F_IN, false><<<gb, 256, 0, stream>>>(x, Wp1, dinv, hA8);          // h1' fp8
    agg_fp8<1><<<agg_nb, 256, 0, stream>>>(hA8, dinv, rowdeg, colsrc, b1, hB);  // z1 bf16
    gemm_mfma<H_DIM, true><<<gb, 256, 0, stream>>>(hB, Wp2, dinv, hA8);         // h2' fp8
    agg_fp8<0><<<agg_nb, 256, 0, stream>>>(hA8, dinv, rowdeg, colsrc, b2, hB);  // z2 bf16
    pool_head<<<N_GRAPH, 256, 0, stream>>>(hB, batch, Wl, bl, out);
}